// Round 5
// baseline (1647.910 us; speedup 1.0000x reference)
//
#include <hip/hip_runtime.h>
#include <cstdint>
#include <cstddef>

#define M_ROWS 32768   // B*T
#define K_CODES 8192
#define H_DIM 512
#define TAU 2.5e-4f
#define MAXFLAG 32768

typedef float  f32x4 __attribute__((ext_vector_type(4)));
typedef short  s16x8 __attribute__((ext_vector_type(8)));

typedef __attribute__((address_space(3))) void as3_void;
typedef const __attribute__((address_space(1))) void as1_cvoid;
#define GLD16(gp, lp) __builtin_amdgcn_global_load_lds((as1_cvoid*)(gp), (as3_void*)(lp), 16, 0, 0)

// ---------------------------------------------------------------------------
// bf16 split helpers (RNE)
// ---------------------------------------------------------------------------
__device__ __forceinline__ unsigned short f2bf(float f) {
    uint32_t u = __float_as_uint(f);
    u = u + 0x7fffu + ((u >> 16) & 1u);
    return (unsigned short)(u >> 16);
}
__device__ __forceinline__ float bf2f(unsigned short h) {
    return __uint_as_float(((uint32_t)h) << 16);
}

// fused split of z AND emb: fp32 -> (hi, lo) bf16, 1 float4 per thread
__global__ __launch_bounds__(256) void split_all_kernel(
    const float* __restrict__ z, const float* __restrict__ emb,
    unsigned short* __restrict__ zh, unsigned short* __restrict__ zl,
    unsigned short* __restrict__ eh, unsigned short* __restrict__ el)
{
    const int ZQ = M_ROWS * H_DIM / 4;    // 4,194,304
    const int EQ = K_CODES * H_DIM / 4;   // 1,048,576
    int t = blockIdx.x * 256 + threadIdx.x;
    const float* src; unsigned short* hi; unsigned short* lo;
    if (t < ZQ)           { src = z;   hi = zh; lo = zl; }
    else if (t < ZQ + EQ) { t -= ZQ; src = emb; hi = eh; lo = el; }
    else return;
    const float4 v = reinterpret_cast<const float4*>(src)[t];
    ushort4 h, l;
    h.x = f2bf(v.x); l.x = f2bf(v.x - bf2f(h.x));
    h.y = f2bf(v.y); l.y = f2bf(v.y - bf2f(h.y));
    h.z = f2bf(v.z); l.z = f2bf(v.z - bf2f(h.z));
    h.w = f2bf(v.w); l.w = f2bf(v.w - bf2f(h.w));
    reinterpret_cast<ushort4*>(hi)[t] = h;
    reinterpret_cast<ushort4*>(lo)[t] = l;
}

// ---------------------------------------------------------------------------
// numpy pairwise sum-of-squares (bit-exact), 32 lanes per row
// ---------------------------------------------------------------------------
__device__ __forceinline__ float np_sumsq_row32(const float* __restrict__ row,
                                                int lane32) {
    const int c = lane32 >> 3, j = lane32 & 7;
    const float* p = row + c * 128 + j;
    float s = __fmul_rn(p[0], p[0]);
    #pragma unroll
    for (int t = 1; t < 16; ++t) {
        const float v = p[8 * t];
        s = __fadd_rn(s, __fmul_rn(v, v));
    }
    s = __fadd_rn(s, __shfl_xor(s, 1));
    s = __fadd_rn(s, __shfl_xor(s, 2));
    s = __fadd_rn(s, __shfl_xor(s, 4));
    s = __fadd_rn(s, __shfl_xor(s, 8));
    s = __fadd_rn(s, __shfl_xor(s, 16));
    return s;
}

// fused: x2 for z rows AND e2 for emb rows; 8 rows per block
__global__ __launch_bounds__(256) void rowsq_all_kernel(
    const float* __restrict__ z, const float* __restrict__ emb,
    float* __restrict__ x2, float* __restrict__ e2,
    float* __restrict__ loss_slots, int* __restrict__ flag_count)
{
    const int slot = blockIdx.x * 8 + (threadIdx.x >> 5);
    if (slot < M_ROWS) {
        const float s = np_sumsq_row32(z + (size_t)slot * H_DIM, threadIdx.x & 31);
        if ((threadIdx.x & 31) == 0) x2[slot] = s;
    } else if (slot < M_ROWS + K_CODES) {
        const int r = slot - M_ROWS;
        const float s = np_sumsq_row32(emb + (size_t)r * H_DIM, threadIdx.x & 31);
        if ((threadIdx.x & 31) == 0) e2[r] = s;
    }
    if (blockIdx.x == 0) {
        if (threadIdx.x < 2) loss_slots[threadIdx.x] = 0.f;
        if (threadIdx.x == 0) *flag_count = 0;
    }
}

// ---------------------------------------------------------------------------
// top-2 merge helper
// ---------------------------------------------------------------------------
__device__ __forceinline__ void top2_merge(float& b1, int& ix, float& b2,
                                           float ob1, int oix, float ob2) {
    if (ob1 < b1)      { b2 = fminf(b1, ob2); b1 = ob1; ix = oix; }
    else if (ob1 > b1) { b2 = fminf(b2, ob1); }
    else               { if (oix < ix) ix = oix; b2 = b1; }
}

// ---------------------------------------------------------------------------
// MFMA distance GEMM + top-2 argmin, 2-phase double-buffered pipeline.
// Tile 128x128, BK=32, 4 waves; flat 512-step loop (32 code-tiles x 16 K-steps).
// LDS: 2 parities x {Ah,Al,Bh,Bl} x [128 rows][32 k] bf16 (8KB each) = 64 KB.
// Swizzle: 16B slot p = chunk ^ ((row>>1)&3), applied on the global SOURCE
// (linear LDS dest for global_load_lds) and on the ds_read address.
// Each wave stages exactly one array per step (8 x GLD16 = 8KB).
// d = fl(fl(x2 - 2g) + e2)  (np rounding order).
// ---------------------------------------------------------------------------
__global__ __launch_bounds__(256, 2) void mfma_dist_kernel(
    const unsigned short* __restrict__ zh, const unsigned short* __restrict__ zl,
    const unsigned short* __restrict__ eh, const unsigned short* __restrict__ el,
    const float* __restrict__ x2, const float* __restrict__ e2,
    float* __restrict__ pb1, float* __restrict__ pb2, int* __restrict__ pidx)
{
    __shared__ __align__(16) unsigned short lb[2][4][4096];   // 64 KiB
    __shared__ float rb1[2][128];
    __shared__ float rb2[2][128];
    __shared__ int   ri [2][128];

    const int tid = threadIdx.x;
    const int l   = tid & 63;
    const int w   = tid >> 6;
    const int wm  = w >> 1, wn = w & 1;
    const int row0 = blockIdx.x * 128;
    const int c0   = blockIdx.y * (K_CODES / 2);
    const int NSTEP = 32 * 16;   // 32 code-tiles x 16 K-steps

    // --- staging geometry (wave w owns array w: 0=Ah 1=Al 2=Bh 3=Bl) ---
    const unsigned short* sp = (w == 0) ? zh : (w == 1) ? zl : (w == 2) ? eh : el;
    const bool isA = (w < 2);
    // per-lane source offsets: row-within-16 = l>>2, swizzled 8-elem chunk
    const int srow = l >> 2;
    const int scol = ((l & 3) ^ ((l >> 3) & 3)) * 8;
    const size_t slane = (size_t)srow * H_DIM + scol;

    // --- ds_read geometry ---
    // A frag lane l: row l&15 (+16i +64wm), k-chunk l>>4; swizzle slot ^ ((row>>1)&3)
    const int abyte = (wm * 64 + (l & 15)) * 64 + (((l >> 4) ^ ((l >> 1) & 3)) * 16);
    const int bbyte = (wn * 64 + (l & 15)) * 64 + (((l >> 4) ^ ((l >> 1) & 3)) * 16);

    float x2r[16];
    #pragma unroll
    for (int i = 0; i < 4; ++i)
        #pragma unroll
        for (int r = 0; r < 4; ++r)
            x2r[i * 4 + r] = x2[row0 + wm * 64 + i * 16 + (l >> 4) * 4 + r];

    float tb1[16], tb2[16]; int tix[16];
    #pragma unroll
    for (int s = 0; s < 16; ++s) { tb1[s] = 3.4e38f; tb2[s] = 3.4e38f; tix[s] = 0; }

    f32x4 acc[4][4];
    #pragma unroll
    for (int i = 0; i < 4; ++i)
        #pragma unroll
        for (int j = 0; j < 4; ++j)
            acc[i][j] = (f32x4){0.f, 0.f, 0.f, 0.f};

    // --- prologue: stage step 0 into parity 0 ---
    {
        const int rbase = isA ? row0 : c0;
        const unsigned short* sb = sp + (size_t)rbase * H_DIM + slane;
        char* dst = (char*)&lb[0][w][0];
        #pragma unroll
        for (int t = 0; t < 8; ++t)
            GLD16(sb + (size_t)t * 16 * H_DIM, dst + t * 1024);
    }
    __syncthreads();   // drains vmcnt(0) + lgkmcnt(0)

    for (int s = 0; s < NSTEP; ++s) {
        const int par = s & 1;

        // stage step s+1 into the other parity (overlaps with compute below)
        if (s + 1 < NSTEP) {
            const int nt1 = (s + 1) >> 4;
            const int hc1 = (s + 1) & 15;
            const int rbase = isA ? row0 : (c0 + nt1 * 128);
            const unsigned short* sb = sp + (size_t)rbase * H_DIM + hc1 * 32 + slane;
            char* dst = (char*)&lb[par ^ 1][w][0];
            #pragma unroll
            for (int t = 0; t < 8; ++t)
                GLD16(sb + (size_t)t * 16 * H_DIM, dst + t * 1024);
        }
        __builtin_amdgcn_sched_barrier(0);   // pin stage issue before compute

        // ds_read current parity fragments
        const char* pA  = (const char*)&lb[par][0][0];
        const char* pAl = (const char*)&lb[par][1][0];
        const char* pB  = (const char*)&lb[par][2][0];
        const char* pBl = (const char*)&lb[par][3][0];
        s16x8 ah[4], av[4], bh[4], bv[4];
        #pragma unroll
        for (int i = 0; i < 4; ++i) {
            ah[i] = *(const s16x8*)(pA  + abyte + i * 1024);
            av[i] = *(const s16x8*)(pAl + abyte + i * 1024);
            bh[i] = *(const s16x8*)(pB  + bbyte + i * 1024);
            bv[i] = *(const s16x8*)(pBl + bbyte + i * 1024);
        }

        __builtin_amdgcn_s_setprio(1);
        #pragma unroll
        for (int i = 0; i < 4; ++i)
            #pragma unroll
            for (int j = 0; j < 4; ++j) {
                acc[i][j] = __builtin_amdgcn_mfma_f32_16x16x32_bf16(av[i], bh[j], acc[i][j], 0, 0, 0);
                acc[i][j] = __builtin_amdgcn_mfma_f32_16x16x32_bf16(ah[i], bv[j], acc[i][j], 0, 0, 0);
                acc[i][j] = __builtin_amdgcn_mfma_f32_16x16x32_bf16(ah[i], bh[j], acc[i][j], 0, 0, 0);
            }
        __builtin_amdgcn_s_setprio(0);

        // code-tile boundary: fold e2/x2, update top-2, reset acc
        if ((s & 15) == 15) {
            const int nt = s >> 4;
            #pragma unroll
            for (int j = 0; j < 4; ++j) {
                const int cj = c0 + nt * 128 + wn * 64 + j * 16 + (l & 15);
                const float e2v = e2[cj];
                #pragma unroll
                for (int i = 0; i < 4; ++i)
                    #pragma unroll
                    for (int r = 0; r < 4; ++r) {
                        const float d = __fadd_rn(__fmaf_rn(-2.f, acc[i][j][r], x2r[i * 4 + r]), e2v);
                        const int st = i * 4 + r;
                        if (d < tb1[st])      { tb2[st] = tb1[st]; tb1[st] = d; tix[st] = cj; }
                        else if (d < tb2[st]) { tb2[st] = d; }
                        acc[i][j][r] = 0.f;
                    }
            }
        }

        __syncthreads();   // publishes parity^1, protects parity (full drain)
    }

    // 16-lane top-2 reduce per state
    #pragma unroll
    for (int s = 0; s < 16; ++s) {
        float b1 = tb1[s], b2 = tb2[s]; int ix = tix[s];
        #pragma unroll
        for (int m = 1; m <= 8; m <<= 1) {
            const float ob1 = __shfl_xor(b1, m);
            const float ob2 = __shfl_xor(b2, m);
            const int   oix = __shfl_xor(ix, m);
            top2_merge(b1, ix, b2, ob1, oix, ob2);
        }
        tb1[s] = b1; tb2[s] = b2; tix[s] = ix;
    }
    if ((l & 15) == 0) {
        const int q = l >> 4;
        #pragma unroll
        for (int i = 0; i < 4; ++i)
            #pragma unroll
            for (int r = 0; r < 4; ++r) {
                const int rl = wm * 64 + i * 16 + q * 4 + r;
                rb1[wn][rl] = tb1[i * 4 + r];
                rb2[wn][rl] = tb2[i * 4 + r];
                ri [wn][rl] = tix[i * 4 + r];
            }
    }
    __syncthreads();
    if (tid < 128) {
        float b1 = rb1[0][tid], b2 = rb2[0][tid]; int ix = ri[0][tid];
        top2_merge(b1, ix, b2, rb1[1][tid], ri[1][tid], rb2[1][tid]);
        const size_t o = (size_t)blockIdx.y * M_ROWS + row0 + tid;
        pb1[o] = b1; pb2[o] = b2; pidx[o] = ix;
    }
}

// merge the 2 code-split partials per row; emit idx + ambiguity flags
__global__ __launch_bounds__(256) void combine_kernel(
    const float* __restrict__ pb1, const float* __restrict__ pb2,
    const int* __restrict__ pidx,
    int* __restrict__ idx_i, float* __restrict__ idx_f,
    int* __restrict__ flag_count, int* __restrict__ flag_rows)
{
    const int r = blockIdx.x * 256 + threadIdx.x;
    if (r >= M_ROWS) return;
    float b1 = pb1[r], b2 = pb2[r]; int ix = pidx[r];
    top2_merge(b1, ix, b2, pb1[M_ROWS + r], pidx[M_ROWS + r], pb2[M_ROWS + r]);
    idx_i[r] = ix;
    idx_f[r] = (float)ix;
    if (b2 - b1 < TAU) {
        const int p = atomicAdd(flag_count, 1);
        if (p < MAXFLAG) flag_rows[p] = r;
    }
}

// ---------------------------------------------------------------------------
// FALLBACK (round-3 fp32 path) — only if ws_size too small
// ---------------------------------------------------------------------------
#define BM 64
#define BN 128
#define BH 32
#define PADZ 4
#define PADE 4

__device__ __forceinline__ void stage_transposed(const float* __restrict__ src,
                                                 int row0, int h0,
                                                 float* lds, int R, int ldp) {
    const int nf4 = R * (BH / 4);
    for (int f = threadIdx.x; f < nf4; f += 256) {
        const int r  = f / (BH / 4);
        const int c4 = (f % (BH / 4)) * 4;
        const float4 v = *reinterpret_cast<const float4*>(
            src + (size_t)(row0 + r) * H_DIM + h0 + c4);
        lds[(c4 + 0) * ldp + r] = v.x;
        lds[(c4 + 1) * ldp + r] = v.y;
        lds[(c4 + 2) * ldp + r] = v.z;
        lds[(c4 + 3) * ldp + r] = v.w;
    }
}

__global__ __launch_bounds__(256) void dist_argmin_kernel(
    const float* __restrict__ z, const float* __restrict__ emb,
    const float* __restrict__ x2, const float* __restrict__ e2,
    int* __restrict__ idx_i, float* __restrict__ idx_f,
    int* __restrict__ flag_count, int* __restrict__ flag_rows)
{
    __shared__ float zs[BH * (BM + PADZ)];
    __shared__ float es[BH * (BN + PADE)];
    __shared__ float bd[BM][17];
    __shared__ float bd2[BM][17];
    __shared__ int   bi[BM][17];

    const int row0 = blockIdx.x * BM;
    const int tx = threadIdx.x & 15;
    const int ty = threadIdx.x >> 4;

    float x2r[4];
    #pragma unroll
    for (int i = 0; i < 4; ++i) x2r[i] = x2[row0 + ty * 4 + i];

    float best[4], best2[4];
    int   bidx[4];
    #pragma unroll
    for (int i = 0; i < 4; ++i) { best[i] = 3.4e38f; best2[i] = 3.4e38f; bidx[i] = 0; }

    for (int nt = 0; nt < K_CODES / BN; ++nt) {
        float acc[4][8];
        #pragma unroll
        for (int i = 0; i < 4; ++i)
            #pragma unroll
            for (int j = 0; j < 8; ++j) acc[i][j] = 0.f;

        for (int hc = 0; hc < H_DIM / BH; ++hc) {
            __syncthreads();
            stage_transposed(z,   row0,    hc * BH, zs, BM, BM + PADZ);
            stage_transposed(emb, nt * BN, hc * BH, es, BN, BN + PADE);
            __syncthreads();
            #pragma unroll
            for (int h = 0; h < BH; ++h) {
                const float4 zr = *reinterpret_cast<const float4*>(&zs[h * (BM + PADZ) + ty * 4]);
                const float4 e0 = *reinterpret_cast<const float4*>(&es[h * (BN + PADE) + tx * 4]);
                const float4 e1 = *reinterpret_cast<const float4*>(&es[h * (BN + PADE) + 64 + tx * 4]);
                const float zrv[4] = {zr.x, zr.y, zr.z, zr.w};
                const float ev[8]  = {e0.x, e0.y, e0.z, e0.w, e1.x, e1.y, e1.z, e1.w};
                #pragma unroll
                for (int i = 0; i < 4; ++i)
                    #pragma unroll
                    for (int j = 0; j < 8; ++j)
                        acc[i][j] = fmaf(zrv[i], ev[j], acc[i][j]);
            }
        }
        #pragma unroll
        for (int j = 0; j < 8; ++j) {
            const int code = nt * BN + (j < 4 ? tx * 4 + j : 64 + tx * 4 + (j - 4));
            const float e2v = e2[code];
            #pragma unroll
            for (int i = 0; i < 4; ++i) {
                const float d = __fadd_rn(__fmaf_rn(-2.f, acc[i][j], x2r[i]), e2v);
                if (d < best[i])       { best2[i] = best[i]; best[i] = d; bidx[i] = code; }
                else if (d < best2[i]) { best2[i] = d; }
            }
        }
    }

    __syncthreads();
    #pragma unroll
    for (int i = 0; i < 4; ++i) {
        bd [ty * 4 + i][tx] = best[i];
        bd2[ty * 4 + i][tx] = best2[i];
        bi [ty * 4 + i][tx] = bidx[i];
    }
    __syncthreads();
    if (threadIdx.x < BM) {
        const int r = threadIdx.x;
        float g1 = bd[r][0]; int gi = bi[r][0]; float g2 = bd2[r][0];
        #pragma unroll
        for (int t = 1; t < 16; ++t) {
            const float v = bd[r][t]; const int x = bi[r][t];
            if (v < g1)       { g2 = g1; g1 = v; gi = x; }
            else if (v == g1) { g2 = g1; if (x < gi) gi = x; }
            else              { g2 = fminf(g2, v); }
            g2 = fminf(g2, bd2[r][t]);
        }
        idx_i[row0 + r] = gi;
        idx_f[row0 + r] = (float)gi;
        if (g2 - g1 < TAU) {
            const int p = atomicAdd(flag_count, 1);
            if (p < MAXFLAG) flag_rows[p] = row0 + r;
        }
    }
}

// ---------------------------------------------------------------------------
// fixup: ideal-g (fp64 dot -> fp32) rescore, 4-way ILP fp64 chain
// ---------------------------------------------------------------------------
__global__ __launch_bounds__(256) void fixup_kernel(
    const float* __restrict__ z, const float* __restrict__ emb,
    const float* __restrict__ x2, const float* __restrict__ e2,
    const int* __restrict__ flag_count, const int* __restrict__ flag_rows,
    int* __restrict__ idx_i, float* __restrict__ idx_f)
{
    __shared__ float zrow[H_DIM];
    __shared__ float sd[256];
    __shared__ int   si[256];
    int n = *flag_count; if (n > MAXFLAG) n = MAXFLAG;
    for (int j = blockIdx.x; j < n; j += gridDim.x) {
        const int row = flag_rows[j];
        __syncthreads();
        for (int h = threadIdx.x; h < H_DIM; h += 256)
            zrow[h] = z[(size_t)row * H_DIM + h];
        __syncthreads();
        const float x2r = x2[row];
        float bdv = 3.4e38f; int biv = 0x7fffffff;
        for (int k = threadIdx.x; k < K_CODES; k += 256) {
            const float* ek = emb + (size_t)k * H_DIM;
            double d0 = 0.0, d1 = 0.0, d2 = 0.0, d3 = 0.0;
            for (int h = 0; h < H_DIM; h += 4) {
                const float4 ev = *reinterpret_cast<const float4*>(ek + h);
                const float4 zv = *reinterpret_cast<const float4*>(&zrow[h]);
                d0 = fma((double)zv.x, (double)ev.x, d0);
                d1 = fma((double)zv.y, (double)ev.y, d1);
                d2 = fma((double)zv.z, (double)ev.z, d2);
                d3 = fma((double)zv.w, (double)ev.w, d3);
            }
            const float gf = (float)((d0 + d1) + (d2 + d3));
            const float d = __fadd_rn(__fmaf_rn(-2.f, gf, x2r), e2[k]);
            if (d < bdv) { bdv = d; biv = k; }
        }
        sd[threadIdx.x] = bdv; si[threadIdx.x] = biv;
        __syncthreads();
        for (int s = 128; s; s >>= 1) {
            if (threadIdx.x < s) {
                const float od = sd[threadIdx.x + s]; const int oi = si[threadIdx.x + s];
                if (od < sd[threadIdx.x] ||
                    (od == sd[threadIdx.x] && oi < si[threadIdx.x])) {
                    sd[threadIdx.x] = od; si[threadIdx.x] = oi;
                }
            }
            __syncthreads();
        }
        if (threadIdx.x == 0) { idx_i[row] = si[0]; idx_f[row] = (float)si[0]; }
        __syncthreads();
    }
}

// ---------------------------------------------------------------------------
// z_st = z + (z_q - z) + both losses; float4 vectorized
// ---------------------------------------------------------------------------
__global__ __launch_bounds__(256) void epilogue_kernel(
    const float* __restrict__ z, const float* __restrict__ emb,
    const int* __restrict__ idx_i,
    float* __restrict__ z_st, float* __restrict__ loss_slots)
{
    const int NQ = M_ROWS * (H_DIM / 4);   // 4,194,304 float4
    const float4* z4 = reinterpret_cast<const float4*>(z);
    const float4* e4 = reinterpret_cast<const float4*>(emb);
    float4* o4 = reinterpret_cast<float4*>(z_st);
    float local = 0.f;
    for (int q = blockIdx.x * 256 + threadIdx.x; q < NQ; q += gridDim.x * 256) {
        const int r  = q >> 7;             // H_DIM/4 = 128
        const int h4 = q & 127;
        const float4 zq = e4[(size_t)idx_i[r] * 128 + h4];
        const float4 zv = z4[q];
        float4 t, o;
        t.x = zq.x - zv.x; o.x = zv.x + t.x;
        t.y = zq.y - zv.y; o.y = zv.y + t.y;
        t.z = zq.z - zv.z; o.z = zv.z + t.z;
        t.w = zq.w - zv.w; o.w = zv.w + t.w;
        o4[q] = o;
        local = fmaf(t.x, t.x, local);
        local = fmaf(t.y, t.y, local);
        local = fmaf(t.z, t.z, local);
        local = fmaf(t.w, t.w, local);
    }
    #pragma unroll
    for (int off = 32; off; off >>= 1) local += __shfl_down(local, off);
    __shared__ float part[4];
    const int lane = threadIdx.x & 63, wid = threadIdx.x >> 6;
    if (lane == 0) part[wid] = local;
    __syncthreads();
    if (threadIdx.x == 0) {
        const float s = (part[0] + part[1] + part[2] + part[3])
                        * (1.f / (float)((size_t)M_ROWS * H_DIM));
        atomicAdd(&loss_slots[0], s);
        atomicAdd(&loss_slots[1], s);
    }
}

// ---------------------------------------------------------------------------
extern "C" void kernel_launch(void* const* d_in, const int* in_sizes, int n_in,
                              void* d_out, int out_size, void* d_ws, size_t ws_size,
                              hipStream_t stream) {
    const float* z   = (const float*)d_in[0];
    const float* emb = (const float*)d_in[1];

    float* out   = (float*)d_out;
    float* z_st  = out;
    float* idx_f = out + (size_t)M_ROWS * H_DIM;
    float* loss  = out + (size_t)M_ROWS * H_DIM + M_ROWS;

    char* ws = (char*)d_ws;
    float* e2     = (float*)(ws + 0);
    float* x2     = (float*)(ws + 32768);
    int*   idx_i  = (int*)  (ws + 163840);
    int*   fcount = (int*)  (ws + 294912);
    int*   frows  = (int*)  (ws + 294976);
    float* pb1    = (float*)(ws + 426048);
    float* pb2    = (float*)(ws + 688192);
    int*   pidx   = (int*)  (ws + 950336);
    unsigned short* zh = (unsigned short*)(ws + 1212480);
    unsigned short* zl = (unsigned short*)(ws + 1212480 + 33554432ull);
    unsigned short* eh = (unsigned short*)(ws + 1212480 + 67108864ull);
    unsigned short* el = (unsigned short*)(ws + 1212480 + 75497472ull);
    const size_t REQ = 1212480ull + 75497472ull + 8388608ull;   // ~85.1 MB

    hipLaunchKernelGGL(rowsq_all_kernel, dim3((M_ROWS + K_CODES) / 8), dim3(256), 0, stream,
                       z, emb, x2, e2, loss, fcount);

    if (ws_size >= REQ) {
        const int totq = (M_ROWS * H_DIM + K_CODES * H_DIM) / 4;
        hipLaunchKernelGGL(split_all_kernel, dim3(totq / 256), dim3(256), 0, stream,
                           z, emb, zh, zl, eh, el);
        hipLaunchKernelGGL(mfma_dist_kernel, dim3(M_ROWS / 128, 2), dim3(256), 0, stream,
                           zh, zl, eh, el, x2, e2, pb1, pb2, pidx);
        hipLaunchKernelGGL(combine_kernel, dim3(M_ROWS / 256), dim3(256), 0, stream,
                           pb1, pb2, pidx, idx_i, idx_f, fcount, frows);
    } else {
        hipLaunchKernelGGL(dist_argmin_kernel, dim3(M_ROWS / BM), dim3(256), 0, stream,
                           z, emb, x2, e2, idx_i, idx_f, fcount, frows);
    }

    hipLaunchKernelGGL(fixup_kernel, dim3(64), dim3(256), 0, stream,
                       z, emb, x2, e2, fcount, frows, idx_i, idx_f);
    hipLaunchKernelGGL(epilogue_kernel, dim3(2048), dim3(256), 0, stream,
                       z, emb, idx_i, z_st, loss);
}

// Round 6
// 1554.418 us; speedup vs baseline: 1.0601x; 1.0601x over previous
//
#include <hip/hip_runtime.h>
#include <cstdint>
#include <cstddef>

#define M_ROWS 32768   // B*T
#define K_CODES 8192
#define H_DIM 512
#define TAU 2.5e-4f
#define MAXFLAG 32768

typedef float  f32x4 __attribute__((ext_vector_type(4)));
typedef short  s16x8 __attribute__((ext_vector_type(8)));

typedef __attribute__((address_space(3))) void as3_void;
typedef const __attribute__((address_space(1))) void as1_cvoid;
#define GLD16(gp, lp) __builtin_amdgcn_global_load_lds((as1_cvoid*)(gp), (as3_void*)(lp), 16, 0, 0)

// ---------------------------------------------------------------------------
// bf16 split helpers (RNE)
// ---------------------------------------------------------------------------
__device__ __forceinline__ unsigned short f2bf(float f) {
    uint32_t u = __float_as_uint(f);
    u = u + 0x7fffu + ((u >> 16) & 1u);
    return (unsigned short)(u >> 16);
}
__device__ __forceinline__ float bf2f(unsigned short h) {
    return __uint_as_float(((uint32_t)h) << 16);
}

// fused split of z AND emb: fp32 -> (hi, lo) bf16, 1 float4 per thread
__global__ __launch_bounds__(256) void split_all_kernel(
    const float* __restrict__ z, const float* __restrict__ emb,
    unsigned short* __restrict__ zh, unsigned short* __restrict__ zl,
    unsigned short* __restrict__ eh, unsigned short* __restrict__ el)
{
    const int ZQ = M_ROWS * H_DIM / 4;
    const int EQ = K_CODES * H_DIM / 4;
    int t = blockIdx.x * 256 + threadIdx.x;
    const float* src; unsigned short* hi; unsigned short* lo;
    if (t < ZQ)           { src = z;   hi = zh; lo = zl; }
    else if (t < ZQ + EQ) { t -= ZQ; src = emb; hi = eh; lo = el; }
    else return;
    const float4 v = reinterpret_cast<const float4*>(src)[t];
    ushort4 h, l;
    h.x = f2bf(v.x); l.x = f2bf(v.x - bf2f(h.x));
    h.y = f2bf(v.y); l.y = f2bf(v.y - bf2f(h.y));
    h.z = f2bf(v.z); l.z = f2bf(v.z - bf2f(h.z));
    h.w = f2bf(v.w); l.w = f2bf(v.w - bf2f(h.w));
    reinterpret_cast<ushort4*>(hi)[t] = h;
    reinterpret_cast<ushort4*>(lo)[t] = l;
}

// ---------------------------------------------------------------------------
// numpy pairwise sum-of-squares (bit-exact), 32 lanes per row
// ---------------------------------------------------------------------------
__device__ __forceinline__ float np_sumsq_row32(const float* __restrict__ row,
                                                int lane32) {
    const int c = lane32 >> 3, j = lane32 & 7;
    const float* p = row + c * 128 + j;
    float s = __fmul_rn(p[0], p[0]);
    #pragma unroll
    for (int t = 1; t < 16; ++t) {
        const float v = p[8 * t];
        s = __fadd_rn(s, __fmul_rn(v, v));
    }
    s = __fadd_rn(s, __shfl_xor(s, 1));
    s = __fadd_rn(s, __shfl_xor(s, 2));
    s = __fadd_rn(s, __shfl_xor(s, 4));
    s = __fadd_rn(s, __shfl_xor(s, 8));
    s = __fadd_rn(s, __shfl_xor(s, 16));
    return s;
}

__global__ __launch_bounds__(256) void rowsq_all_kernel(
    const float* __restrict__ z, const float* __restrict__ emb,
    float* __restrict__ x2, float* __restrict__ e2,
    float* __restrict__ loss_slots, int* __restrict__ flag_count)
{
    const int slot = blockIdx.x * 8 + (threadIdx.x >> 5);
    if (slot < M_ROWS) {
        const float s = np_sumsq_row32(z + (size_t)slot * H_DIM, threadIdx.x & 31);
        if ((threadIdx.x & 31) == 0) x2[slot] = s;
    } else if (slot < M_ROWS + K_CODES) {
        const int r = slot - M_ROWS;
        const float s = np_sumsq_row32(emb + (size_t)r * H_DIM, threadIdx.x & 31);
        if ((threadIdx.x & 31) == 0) e2[r] = s;
    }
    if (blockIdx.x == 0) {
        if (threadIdx.x < 2) loss_slots[threadIdx.x] = 0.f;
        if (threadIdx.x == 0) *flag_count = 0;
    }
}

// ---------------------------------------------------------------------------
// top-2 merge helper
// ---------------------------------------------------------------------------
__device__ __forceinline__ void top2_merge(float& b1, int& ix, float& b2,
                                           float ob1, int oix, float ob2) {
    if (ob1 < b1)      { b2 = fminf(b1, ob2); b1 = ob1; ix = oix; }
    else if (ob1 > b1) { b2 = fminf(b2, ob1); }
    else               { if (oix < ix) ix = oix; b2 = b1; }
}

// ---------------------------------------------------------------------------
// MFMA distance GEMM + top-2 argmin. T4 pipeline: counted vmcnt + raw
// s_barrier (loads stay in flight across barriers; NEVER vmcnt(0) in loop).
// Tile 128x128, BK=32, dbuf parities, 4 waves (wave w stages array w).
// LDS: 2 x {Ah,Al,Bh,Bl} x [128][32] bf16 = 64 KB  +  e2 panel 16 KB = 80 KB
// (cross-wave merge reuses the staging buffer after the loop) -> 2 blocks/CU.
// Swizzle (verified r5): store slot = chunk ^ ((row>>1)&3) via pre-swizzled
// global source, read addr uses same XOR. d = fl(fl(x2-2g)+e2)  (np order).
// ---------------------------------------------------------------------------
__global__ __launch_bounds__(256, 2) void mfma_dist_kernel(
    const unsigned short* __restrict__ zh, const unsigned short* __restrict__ zl,
    const unsigned short* __restrict__ eh, const unsigned short* __restrict__ el,
    const float* __restrict__ x2, const float* __restrict__ e2,
    float* __restrict__ pb1, float* __restrict__ pb2, int* __restrict__ pidx)
{
    __shared__ __align__(16) unsigned short lb[2][4][4096];   // 64 KiB
    __shared__ __align__(16) float e2s[4096];                 // 16 KiB

    const int tid = threadIdx.x;
    const int l   = tid & 63;
    const int w   = tid >> 6;
    const int wm  = w >> 1, wn = w & 1;
    const int row0 = blockIdx.x * 128;
    const int c0   = blockIdx.y * (K_CODES / 2);

    // --- staging geometry (wave w owns array w: 0=Ah 1=Al 2=Bh 3=Bl) ---
    const unsigned short* sp = (w == 0) ? zh : (w == 1) ? zl : (w == 2) ? eh : el;
    const bool isA = (w < 2);
    const int srow = l >> 2;
    const int scol = ((l & 3) ^ ((l >> 3) & 3)) * 8;   // pre-swizzled source chunk
    // sb points at the data of the NEXT step to stage
    const unsigned short* sb = sp + (size_t)((isA ? row0 : c0) + srow) * H_DIM + scol;
    const ptrdiff_t dwrap = isA ? -480 : (128 * H_DIM - 480);

    // --- ds_read geometry (swizzled, verified r5) ---
    const int abyte = (wm * 64 + (l & 15)) * 64 + (((l >> 4) ^ ((l >> 1) & 3)) * 16);
    const int bbyte = (wn * 64 + (l & 15)) * 64 + (((l >> 4) ^ ((l >> 1) & 3)) * 16);

    float x2r[16];
    #pragma unroll
    for (int i = 0; i < 4; ++i)
        #pragma unroll
        for (int r = 0; r < 4; ++r)
            x2r[i * 4 + r] = x2[row0 + wm * 64 + i * 16 + (l >> 4) * 4 + r];

    // stage e2 panel for this block's 4096 codes into LDS (one-time)
    {
        const float4* s4 = reinterpret_cast<const float4*>(e2 + c0);
        float4* d4 = reinterpret_cast<float4*>(e2s);
        #pragma unroll
        for (int k = 0; k < 4; ++k) d4[tid + k * 256] = s4[tid + k * 256];
    }

    float tb1[16], tb2[16]; int tix[16];
    #pragma unroll
    for (int s = 0; s < 16; ++s) { tb1[s] = 3.4e38f; tb2[s] = 3.4e38f; tix[s] = 0; }

    f32x4 acc[4][4];
    #pragma unroll
    for (int i = 0; i < 4; ++i)
        #pragma unroll
        for (int j = 0; j < 4; ++j)
            acc[i][j] = (f32x4){0.f, 0.f, 0.f, 0.f};

    // --- prologue: stage step 0 into parity 0 ---
    {
        char* dst = (char*)&lb[0][w][0];
        #pragma unroll
        for (int t = 0; t < 8; ++t)
            GLD16(sb + (size_t)t * 16 * H_DIM, dst + t * 1024);
        sb += 32;   // -> step-1 data
    }
    asm volatile("s_waitcnt vmcnt(0) lgkmcnt(0)" ::: "memory");
    __builtin_amdgcn_s_barrier();

    for (int nt = 0; nt < 32; ++nt) {
        #pragma unroll
        for (int hc = 0; hc < 16; ++hc) {
            const int par = hc & 1;
            const bool lastStep = (hc == 15) && (nt == 31);

            // issue stage for step s+1 into parity^1 (stays in flight!)
            if (!lastStep) {
                char* dst = (char*)&lb[par ^ 1][w][0];
                #pragma unroll
                for (int t = 0; t < 8; ++t)
                    GLD16(sb + (size_t)t * 16 * H_DIM, dst + t * 1024);
                sb += (hc == 14) ? dwrap : 32;
            }

            // wait only for the OLDEST 8 loads (this step's data)
            if (!lastStep) asm volatile("s_waitcnt vmcnt(8)" ::: "memory");
            else           asm volatile("s_waitcnt vmcnt(0)" ::: "memory");
            __builtin_amdgcn_s_barrier();

            // ds_read current parity fragments
            const char* pA  = (const char*)&lb[par][0][0];
            const char* pAl = (const char*)&lb[par][1][0];
            const char* pB  = (const char*)&lb[par][2][0];
            const char* pBl = (const char*)&lb[par][3][0];
            s16x8 ah[4], av[4], bh[4], bv[4];
            #pragma unroll
            for (int i = 0; i < 4; ++i) {
                ah[i] = *(const s16x8*)(pA  + abyte + i * 1024);
                av[i] = *(const s16x8*)(pAl + abyte + i * 1024);
                bh[i] = *(const s16x8*)(pB  + bbyte + i * 1024);
                bv[i] = *(const s16x8*)(pBl + bbyte + i * 1024);
            }
            asm volatile("s_waitcnt lgkmcnt(0)" ::: "memory");
            __builtin_amdgcn_s_barrier();   // reads done -> next stage may overwrite

            __builtin_amdgcn_s_setprio(1);
            #pragma unroll
            for (int i = 0; i < 4; ++i)
                #pragma unroll
                for (int j = 0; j < 4; ++j) {
                    acc[i][j] = __builtin_amdgcn_mfma_f32_16x16x32_bf16(av[i], bh[j], acc[i][j], 0, 0, 0);
                    acc[i][j] = __builtin_amdgcn_mfma_f32_16x16x32_bf16(ah[i], bv[j], acc[i][j], 0, 0, 0);
                    acc[i][j] = __builtin_amdgcn_mfma_f32_16x16x32_bf16(ah[i], bh[j], acc[i][j], 0, 0, 0);
                }
            __builtin_amdgcn_s_setprio(0);

            // code-tile boundary: fold e2 (from LDS) / x2, update top-2, reset acc
            if (hc == 15) {
                #pragma unroll
                for (int j = 0; j < 4; ++j) {
                    const int cj  = c0 + nt * 128 + wn * 64 + j * 16 + (l & 15);
                    const float e2v = e2s[nt * 128 + wn * 64 + j * 16 + (l & 15)];
                    #pragma unroll
                    for (int i = 0; i < 4; ++i)
                        #pragma unroll
                        for (int r = 0; r < 4; ++r) {
                            const float d = __fadd_rn(__fmaf_rn(-2.f, acc[i][j][r], x2r[i * 4 + r]), e2v);
                            const int st = i * 4 + r;
                            if (d < tb1[st])      { tb2[st] = tb1[st]; tb1[st] = d; tix[st] = cj; }
                            else if (d < tb2[st]) { tb2[st] = d; }
                            acc[i][j][r] = 0.f;
                        }
                }
            }
        }
    }

    // 16-lane top-2 reduce per state
    #pragma unroll
    for (int s = 0; s < 16; ++s) {
        float b1 = tb1[s], b2 = tb2[s]; int ix = tix[s];
        #pragma unroll
        for (int m = 1; m <= 8; m <<= 1) {
            const float ob1 = __shfl_xor(b1, m);
            const float ob2 = __shfl_xor(b2, m);
            const int   oix = __shfl_xor(ix, m);
            top2_merge(b1, ix, b2, ob1, oix, ob2);
        }
        tb1[s] = b1; tb2[s] = b2; tix[s] = ix;
    }

    // cross-wave merge: reuse the (now dead) staging buffer
    float* rb1 = (float*)&lb[0][0][0];        // [2][128]
    float* rb2 = rb1 + 256;                   // [2][128]
    int*   riB = (int*)(rb1 + 512);           // [2][128]
    if ((l & 15) == 0) {
        const int q = l >> 4;
        #pragma unroll
        for (int i = 0; i < 4; ++i)
            #pragma unroll
            for (int r = 0; r < 4; ++r) {
                const int rl = wn * 128 + wm * 64 + i * 16 + q * 4 + r;
                rb1[rl] = tb1[i * 4 + r];
                rb2[rl] = tb2[i * 4 + r];
                riB[rl] = tix[i * 4 + r];
            }
    }
    __syncthreads();
    if (tid < 128) {
        float b1 = rb1[tid], b2 = rb2[tid]; int ix = riB[tid];
        top2_merge(b1, ix, b2, rb1[128 + tid], riB[128 + tid], rb2[128 + tid]);
        const size_t o = (size_t)blockIdx.y * M_ROWS + row0 + tid;
        pb1[o] = b1; pb2[o] = b2; pidx[o] = ix;
    }
}

// merge the 2 code-split partials per row; emit idx + ambiguity flags
__global__ __launch_bounds__(256) void combine_kernel(
    const float* __restrict__ pb1, const float* __restrict__ pb2,
    const int* __restrict__ pidx,
    int* __restrict__ idx_i, float* __restrict__ idx_f,
    int* __restrict__ flag_count, int* __restrict__ flag_rows)
{
    const int r = blockIdx.x * 256 + threadIdx.x;
    if (r >= M_ROWS) return;
    float b1 = pb1[r], b2 = pb2[r]; int ix = pidx[r];
    top2_merge(b1, ix, b2, pb1[M_ROWS + r], pidx[M_ROWS + r], pb2[M_ROWS + r]);
    idx_i[r] = ix;
    idx_f[r] = (float)ix;
    if (b2 - b1 < TAU) {
        const int p = atomicAdd(flag_count, 1);
        if (p < MAXFLAG) flag_rows[p] = r;
    }
}

// ---------------------------------------------------------------------------
// FALLBACK (round-3 fp32 path) — only if ws_size too small
// ---------------------------------------------------------------------------
#define BM 64
#define BN 128
#define BH 32
#define PADZ 4
#define PADE 4

__device__ __forceinline__ void stage_transposed(const float* __restrict__ src,
                                                 int row0, int h0,
                                                 float* lds, int R, int ldp) {
    const int nf4 = R * (BH / 4);
    for (int f = threadIdx.x; f < nf4; f += 256) {
        const int r  = f / (BH / 4);
        const int c4 = (f % (BH / 4)) * 4;
        const float4 v = *reinterpret_cast<const float4*>(
            src + (size_t)(row0 + r) * H_DIM + h0 + c4);
        lds[(c4 + 0) * ldp + r] = v.x;
        lds[(c4 + 1) * ldp + r] = v.y;
        lds[(c4 + 2) * ldp + r] = v.z;
        lds[(c4 + 3) * ldp + r] = v.w;
    }
}

__global__ __launch_bounds__(256) void dist_argmin_kernel(
    const float* __restrict__ z, const float* __restrict__ emb,
    const float* __restrict__ x2, const float* __restrict__ e2,
    int* __restrict__ idx_i, float* __restrict__ idx_f,
    int* __restrict__ flag_count, int* __restrict__ flag_rows)
{
    __shared__ float zs[BH * (BM + PADZ)];
    __shared__ float es[BH * (BN + PADE)];
    __shared__ float bd[BM][17];
    __shared__ float bd2[BM][17];
    __shared__ int   bi[BM][17];

    const int row0 = blockIdx.x * BM;
    const int tx = threadIdx.x & 15;
    const int ty = threadIdx.x >> 4;

    float x2r[4];
    #pragma unroll
    for (int i = 0; i < 4; ++i) x2r[i] = x2[row0 + ty * 4 + i];

    float best[4], best2[4];
    int   bidx[4];
    #pragma unroll
    for (int i = 0; i < 4; ++i) { best[i] = 3.4e38f; best2[i] = 3.4e38f; bidx[i] = 0; }

    for (int nt = 0; nt < K_CODES / BN; ++nt) {
        float acc[4][8];
        #pragma unroll
        for (int i = 0; i < 4; ++i)
            #pragma unroll
            for (int j = 0; j < 8; ++j) acc[i][j] = 0.f;

        for (int hc = 0; hc < H_DIM / BH; ++hc) {
            __syncthreads();
            stage_transposed(z,   row0,    hc * BH, zs, BM, BM + PADZ);
            stage_transposed(emb, nt * BN, hc * BH, es, BN, BN + PADE);
            __syncthreads();
            #pragma unroll
            for (int h = 0; h < BH; ++h) {
                const float4 zr = *reinterpret_cast<const float4*>(&zs[h * (BM + PADZ) + ty * 4]);
                const float4 e0 = *reinterpret_cast<const float4*>(&es[h * (BN + PADE) + tx * 4]);
                const float4 e1 = *reinterpret_cast<const float4*>(&es[h * (BN + PADE) + 64 + tx * 4]);
                const float zrv[4] = {zr.x, zr.y, zr.z, zr.w};
                const float ev[8]  = {e0.x, e0.y, e0.z, e0.w, e1.x, e1.y, e1.z, e1.w};
                #pragma unroll
                for (int i = 0; i < 4; ++i)
                    #pragma unroll
                    for (int j = 0; j < 8; ++j)
                        acc[i][j] = fmaf(zrv[i], ev[j], acc[i][j]);
            }
        }
        #pragma unroll
        for (int j = 0; j < 8; ++j) {
            const int code = nt * BN + (j < 4 ? tx * 4 + j : 64 + tx * 4 + (j - 4));
            const float e2v = e2[code];
            #pragma unroll
            for (int i = 0; i < 4; ++i) {
                const float d = __fadd_rn(__fmaf_rn(-2.f, acc[i][j], x2r[i]), e2v);
                if (d < best[i])       { best2[i] = best[i]; best[i] = d; bidx[i] = code; }
                else if (d < best2[i]) { best2[i] = d; }
            }
        }
    }

    __syncthreads();
    #pragma unroll
    for (int i = 0; i < 4; ++i) {
        bd [ty * 4 + i][tx] = best[i];
        bd2[ty * 4 + i][tx] = best2[i];
        bi [ty * 4 + i][tx] = bidx[i];
    }
    __syncthreads();
    if (threadIdx.x < BM) {
        const int r = threadIdx.x;
        float g1 = bd[r][0]; int gi = bi[r][0]; float g2 = bd2[r][0];
        #pragma unroll
        for (int t = 1; t < 16; ++t) {
            const float v = bd[r][t]; const int x = bi[r][t];
            if (v < g1)       { g2 = g1; g1 = v; gi = x; }
            else if (v == g1) { g2 = g1; if (x < gi) gi = x; }
            else              { g2 = fminf(g2, v); }
            g2 = fminf(g2, bd2[r][t]);
        }
        idx_i[row0 + r] = gi;
        idx_f[row0 + r] = (float)gi;
        if (g2 - g1 < TAU) {
            const int p = atomicAdd(flag_count, 1);
            if (p < MAXFLAG) flag_rows[p] = row0 + r;
        }
    }
}

// ---------------------------------------------------------------------------
// fixup: ideal-g (fp64 dot -> fp32) rescore, 4-way ILP fp64 chain
// ---------------------------------------------------------------------------
__global__ __launch_bounds__(256) void fixup_kernel(
    const float* __restrict__ z, const float* __restrict__ emb,
    const float* __restrict__ x2, const float* __restrict__ e2,
    const int* __restrict__ flag_count, const int* __restrict__ flag_rows,
    int* __restrict__ idx_i, float* __restrict__ idx_f)
{
    __shared__ float zrow[H_DIM];
    __shared__ float sd[256];
    __shared__ int   si[256];
    int n = *flag_count; if (n > MAXFLAG) n = MAXFLAG;
    for (int j = blockIdx.x; j < n; j += gridDim.x) {
        const int row = flag_rows[j];
        __syncthreads();
        for (int h = threadIdx.x; h < H_DIM; h += 256)
            zrow[h] = z[(size_t)row * H_DIM + h];
        __syncthreads();
        const float x2r = x2[row];
        float bdv = 3.4e38f; int biv = 0x7fffffff;
        for (int k = threadIdx.x; k < K_CODES; k += 256) {
            const float* ek = emb + (size_t)k * H_DIM;
            double d0 = 0.0, d1 = 0.0, d2 = 0.0, d3 = 0.0;
            for (int h = 0; h < H_DIM; h += 4) {
                const float4 ev = *reinterpret_cast<const float4*>(ek + h);
                const float4 zv = *reinterpret_cast<const float4*>(&zrow[h]);
                d0 = fma((double)zv.x, (double)ev.x, d0);
                d1 = fma((double)zv.y, (double)ev.y, d1);
                d2 = fma((double)zv.z, (double)ev.z, d2);
                d3 = fma((double)zv.w, (double)ev.w, d3);
            }
            const float gf = (float)((d0 + d1) + (d2 + d3));
            const float d = __fadd_rn(__fmaf_rn(-2.f, gf, x2r), e2[k]);
            if (d < bdv) { bdv = d; biv = k; }
        }
        sd[threadIdx.x] = bdv; si[threadIdx.x] = biv;
        __syncthreads();
        for (int s = 128; s; s >>= 1) {
            if (threadIdx.x < s) {
                const float od = sd[threadIdx.x + s]; const int oi = si[threadIdx.x + s];
                if (od < sd[threadIdx.x] ||
                    (od == sd[threadIdx.x] && oi < si[threadIdx.x])) {
                    sd[threadIdx.x] = od; si[threadIdx.x] = oi;
                }
            }
            __syncthreads();
        }
        if (threadIdx.x == 0) { idx_i[row] = si[0]; idx_f[row] = (float)si[0]; }
        __syncthreads();
    }
}

// ---------------------------------------------------------------------------
// z_st = z + (z_q - z) + both losses; float4 vectorized
// ---------------------------------------------------------------------------
__global__ __launch_bounds__(256) void epilogue_kernel(
    const float* __restrict__ z, const float* __restrict__ emb,
    const int* __restrict__ idx_i,
    float* __restrict__ z_st, float* __restrict__ loss_slots)
{
    const int NQ = M_ROWS * (H_DIM / 4);
    const float4* z4 = reinterpret_cast<const float4*>(z);
    const float4* e4 = reinterpret_cast<const float4*>(emb);
    float4* o4 = reinterpret_cast<float4*>(z_st);
    float local = 0.f;
    for (int q = blockIdx.x * 256 + threadIdx.x; q < NQ; q += gridDim.x * 256) {
        const int r  = q >> 7;
        const int h4 = q & 127;
        const float4 zq = e4[(size_t)idx_i[r] * 128 + h4];
        const float4 zv = z4[q];
        float4 t, o;
        t.x = zq.x - zv.x; o.x = zv.x + t.x;
        t.y = zq.y - zv.y; o.y = zv.y + t.y;
        t.z = zq.z - zv.z; o.z = zv.z + t.z;
        t.w = zq.w - zv.w; o.w = zv.w + t.w;
        o4[q] = o;
        local = fmaf(t.x, t.x, local);
        local = fmaf(t.y, t.y, local);
        local = fmaf(t.z, t.z, local);
        local = fmaf(t.w, t.w, local);
    }
    #pragma unroll
    for (int off = 32; off; off >>= 1) local += __shfl_down(local, off);
    __shared__ float part[4];
    const int lane = threadIdx.x & 63, wid = threadIdx.x >> 6;
    if (lane == 0) part[wid] = local;
    __syncthreads();
    if (threadIdx.x == 0) {
        const float s = (part[0] + part[1] + part[2] + part[3])
                        * (1.f / (float)((size_t)M_ROWS * H_DIM));
        atomicAdd(&loss_slots[0], s);
        atomicAdd(&loss_slots[1], s);
    }
}

// ---------------------------------------------------------------------------
extern "C" void kernel_launch(void* const* d_in, const int* in_sizes, int n_in,
                              void* d_out, int out_size, void* d_ws, size_t ws_size,
                              hipStream_t stream) {
    const float* z   = (const float*)d_in[0];
    const float* emb = (const float*)d_in[1];

    float* out   = (float*)d_out;
    float* z_st  = out;
    float* idx_f = out + (size_t)M_ROWS * H_DIM;
    float* loss  = out + (size_t)M_ROWS * H_DIM + M_ROWS;

    char* ws = (char*)d_ws;
    float* e2     = (float*)(ws + 0);
    float* x2     = (float*)(ws + 32768);
    int*   idx_i  = (int*)  (ws + 163840);
    int*   fcount = (int*)  (ws + 294912);
    int*   frows  = (int*)  (ws + 294976);
    float* pb1    = (float*)(ws + 426048);
    float* pb2    = (float*)(ws + 688192);
    int*   pidx   = (int*)  (ws + 950336);
    unsigned short* zh = (unsigned short*)(ws + 1212480);
    unsigned short* zl = (unsigned short*)(ws + 1212480 + 33554432ull);
    unsigned short* eh = (unsigned short*)(ws + 1212480 + 67108864ull);
    unsigned short* el = (unsigned short*)(ws + 1212480 + 75497472ull);
    const size_t REQ = 1212480ull + 75497472ull + 8388608ull;   // ~85.1 MB

    hipLaunchKernelGGL(rowsq_all_kernel, dim3((M_ROWS + K_CODES) / 8), dim3(256), 0, stream,
                       z, emb, x2, e2, loss, fcount);

    if (ws_size >= REQ) {
        const int totq = (M_ROWS * H_DIM + K_CODES * H_DIM) / 4;
        hipLaunchKernelGGL(split_all_kernel, dim3(totq / 256), dim3(256), 0, stream,
                           z, emb, zh, zl, eh, el);
        hipLaunchKernelGGL(mfma_dist_kernel, dim3(M_ROWS / 128, 2), dim3(256), 0, stream,
                           zh, zl, eh, el, x2, e2, pb1, pb2, pidx);
        hipLaunchKernelGGL(combine_kernel, dim3(M_ROWS / 256), dim3(256), 0, stream,
                           pb1, pb2, pidx, idx_i, idx_f, fcount, frows);
    } else {
        hipLaunchKernelGGL(dist_argmin_kernel, dim3(M_ROWS / BM), dim3(256), 0, stream,
                           z, emb, x2, e2, idx_i, idx_f, fcount, frows);
    }

    hipLaunchKernelGGL(fixup_kernel, dim3(64), dim3(256), 0, stream,
                       z, emb, x2, e2, fcount, frows, idx_i, idx_f);
    hipLaunchKernelGGL(epilogue_kernel, dim3(2048), dim3(256), 0, stream,
                       z, emb, idx_i, z_st, loss);
}

// Round 7
// 1527.785 us; speedup vs baseline: 1.0786x; 1.0174x over previous
//
#include <hip/hip_runtime.h>
#include <cstdint>
#include <cstddef>

#define M_ROWS 32768   // B*T
#define K_CODES 8192
#define H_DIM 512
#define TAU 2.5e-4f
#define MAXFLAG 32768

typedef float  f32x4 __attribute__((ext_vector_type(4)));
typedef short  s16x8 __attribute__((ext_vector_type(8)));

typedef __attribute__((address_space(3))) void as3_void;
typedef const __attribute__((address_space(1))) void as1_cvoid;
#define GLD16(gp, lp) __builtin_amdgcn_global_load_lds((as1_cvoid*)(gp), (as3_void*)(lp), 16, 0, 0)

// ---------------------------------------------------------------------------
// bf16 split helpers (RNE)
// ---------------------------------------------------------------------------
__device__ __forceinline__ unsigned short f2bf(float f) {
    uint32_t u = __float_as_uint(f);
    u = u + 0x7fffu + ((u >> 16) & 1u);
    return (unsigned short)(u >> 16);
}
__device__ __forceinline__ float bf2f(unsigned short h) {
    return __uint_as_float(((uint32_t)h) << 16);
}

// fused split of z AND emb: fp32 -> (hi, lo) bf16, 1 float4 per thread
__global__ __launch_bounds__(256) void split_all_kernel(
    const float* __restrict__ z, const float* __restrict__ emb,
    unsigned short* __restrict__ zh, unsigned short* __restrict__ zl,
    unsigned short* __restrict__ eh, unsigned short* __restrict__ el)
{
    const int ZQ = M_ROWS * H_DIM / 4;
    const int EQ = K_CODES * H_DIM / 4;
    int t = blockIdx.x * 256 + threadIdx.x;
    const float* src; unsigned short* hi; unsigned short* lo;
    if (t < ZQ)           { src = z;   hi = zh; lo = zl; }
    else if (t < ZQ + EQ) { t -= ZQ; src = emb; hi = eh; lo = el; }
    else return;
    const float4 v = reinterpret_cast<const float4*>(src)[t];
    ushort4 h, l;
    h.x = f2bf(v.x); l.x = f2bf(v.x - bf2f(h.x));
    h.y = f2bf(v.y); l.y = f2bf(v.y - bf2f(h.y));
    h.z = f2bf(v.z); l.z = f2bf(v.z - bf2f(h.z));
    h.w = f2bf(v.w); l.w = f2bf(v.w - bf2f(h.w));
    reinterpret_cast<ushort4*>(hi)[t] = h;
    reinterpret_cast<ushort4*>(lo)[t] = l;
}

// ---------------------------------------------------------------------------
// numpy pairwise sum-of-squares (bit-exact), 32 lanes per row
// ---------------------------------------------------------------------------
__device__ __forceinline__ float np_sumsq_row32(const float* __restrict__ row,
                                                int lane32) {
    const int c = lane32 >> 3, j = lane32 & 7;
    const float* p = row + c * 128 + j;
    float s = __fmul_rn(p[0], p[0]);
    #pragma unroll
    for (int t = 1; t < 16; ++t) {
        const float v = p[8 * t];
        s = __fadd_rn(s, __fmul_rn(v, v));
    }
    s = __fadd_rn(s, __shfl_xor(s, 1));
    s = __fadd_rn(s, __shfl_xor(s, 2));
    s = __fadd_rn(s, __shfl_xor(s, 4));
    s = __fadd_rn(s, __shfl_xor(s, 8));
    s = __fadd_rn(s, __shfl_xor(s, 16));
    return s;
}

__global__ __launch_bounds__(256) void rowsq_all_kernel(
    const float* __restrict__ z, const float* __restrict__ emb,
    float* __restrict__ x2, float* __restrict__ e2,
    float* __restrict__ loss_slots, int* __restrict__ flag_count)
{
    const int slot = blockIdx.x * 8 + (threadIdx.x >> 5);
    if (slot < M_ROWS) {
        const float s = np_sumsq_row32(z + (size_t)slot * H_DIM, threadIdx.x & 31);
        if ((threadIdx.x & 31) == 0) x2[slot] = s;
    } else if (slot < M_ROWS + K_CODES) {
        const int r = slot - M_ROWS;
        const float s = np_sumsq_row32(emb + (size_t)r * H_DIM, threadIdx.x & 31);
        if ((threadIdx.x & 31) == 0) e2[r] = s;
    }
    if (blockIdx.x == 0) {
        if (threadIdx.x < 2) loss_slots[threadIdx.x] = 0.f;
        if (threadIdx.x == 0) *flag_count = 0;
    }
}

// ---------------------------------------------------------------------------
// top-2 merge helper (tie -> lower index)
// ---------------------------------------------------------------------------
__device__ __forceinline__ void top2_merge(float& b1, int& ix, float& b2,
                                           float ob1, int oix, float ob2) {
    if (ob1 < b1)      { b2 = fminf(b1, ob2); b1 = ob1; ix = oix; }
    else if (ob1 > b1) { b2 = fminf(b2, ob1); }
    else               { if (oix < ix) ix = oix; b2 = b1; }
}

// ---------------------------------------------------------------------------
// MFMA distance GEMM + top-2 argmin. 256x256 tile, 8 waves (2m x 4n), BK=32,
// 16 K-steps (full H sweep, NO code re-tiling -> staging traffic halves).
// Counted vmcnt(8) + raw barriers (r6-proven). LDS: 2 par x {Ah,Al,Bh,Bl} x
// [256][32] bf16 = 128 KB. Swizzle (r6-verified): store slot = chunk ^
// ((row>>1)&3) via pre-swizzled global source; same XOR on ds_read.
// Fold once at end: d = fl(fl(x2-2g)+e2) (np order), per-row top-2 partials
// (one per 256-code block column) written to scratch (z_st region).
// Block swizzle: XCD-banded (4 row-tiles per band, ct fastest) for L2 reuse.
// ---------------------------------------------------------------------------
__global__ __launch_bounds__(512, 1) void mfma_dist_kernel(
    const unsigned short* __restrict__ zh, const unsigned short* __restrict__ zl,
    const unsigned short* __restrict__ eh, const unsigned short* __restrict__ el,
    const float* __restrict__ x2, const float* __restrict__ e2,
    float* __restrict__ pb1, float* __restrict__ pb2, int* __restrict__ pidx)
{
    __shared__ __align__(16) unsigned short lb[2][4][8192];   // 128 KiB

    const int tid = threadIdx.x;
    const int l   = tid & 63;
    const int w   = tid >> 6;          // 0..7
    const int wm  = w >> 2;            // 0..1  (row half: 128 rows)
    const int wn  = w & 3;             // 0..3  (code quarter: 64 codes)

    // --- XCD-banded block swizzle: bid -> (rt, ct) ---
    const int bid  = blockIdx.x;          // 0..4095
    const int xcd  = bid & 7;
    const int sq   = bid >> 3;            // 0..511 per XCD
    const int band = sq >> 7;             // 0..3
    const int r128 = sq & 127;
    const int ct   = r128 >> 2;           // 0..31  (fastest)
    const int rt   = (band * 8 + xcd) * 4 + (r128 & 3);   // 0..127
    const int row0 = rt * 256;
    const int c0   = ct * 256;

    // --- staging geometry: wave w stages matrix m = w>>1, row-half = w&1 ---
    const int m    = w >> 1;           // 0=Ah 1=Al 2=Bh 3=Bl
    const int half = w & 1;
    const unsigned short* sp = (m == 0) ? zh : (m == 1) ? zl : (m == 2) ? eh : el;
    const int rbase0 = (m < 2) ? row0 : c0;
    // lane l covers row (half*128 + t*16 + (l>>2)), pre-swizzled 8-elem chunk
    const unsigned short* sb = sp
        + (size_t)(rbase0 + half * 128 + (l >> 2)) * H_DIM
        + ((l & 3) ^ ((l >> 3) & 3)) * 8;

    // --- ds_read geometry (swizzled) ---
    const int aoff = (wm * 128 + (l & 15)) * 64 + (((l >> 4) ^ ((l >> 1) & 3)) * 16);
    const int boff = (wn * 64  + (l & 15)) * 64 + (((l >> 4) ^ ((l >> 1) & 3)) * 16);

    f32x4 acc[8][4];
    #pragma unroll
    for (int i = 0; i < 8; ++i)
        #pragma unroll
        for (int j = 0; j < 4; ++j)
            acc[i][j] = (f32x4){0.f, 0.f, 0.f, 0.f};

    // --- prologue: stage step 0 into parity 0 ---
    {
        char* dst = (char*)&lb[0][m][0] + half * 8192;
        #pragma unroll
        for (int t = 0; t < 8; ++t)
            GLD16(sb + (size_t)t * 16 * H_DIM, dst + t * 1024);
    }

    for (int s = 0; s < 16; ++s) {
        const int par = s & 1;

        if (s < 15) {
            const unsigned short* src = sb + (s + 1) * 32;
            char* dst = (char*)&lb[par ^ 1][m][0] + half * 8192;
            #pragma unroll
            for (int t = 0; t < 8; ++t)
                GLD16(src + (size_t)t * 16 * H_DIM, dst + t * 1024);
            asm volatile("s_waitcnt vmcnt(8)" ::: "memory");   // oldest 8 = step s
        } else {
            asm volatile("s_waitcnt vmcnt(0)" ::: "memory");
        }
        __builtin_amdgcn_s_barrier();

        const char* pAh = (const char*)&lb[par][0][0];
        const char* pAl = (const char*)&lb[par][1][0];
        const char* pBh = (const char*)&lb[par][2][0];
        const char* pBl = (const char*)&lb[par][3][0];

        s16x8 bh[4], bv[4];
        #pragma unroll
        for (int j = 0; j < 4; ++j) {
            bh[j] = *(const s16x8*)(pBh + boff + j * 1024);
            bv[j] = *(const s16x8*)(pBl + boff + j * 1024);
        }
        __builtin_amdgcn_s_setprio(1);
        #pragma unroll
        for (int i = 0; i < 8; ++i) {
            const s16x8 ah = *(const s16x8*)(pAh + aoff + i * 1024);
            const s16x8 av = *(const s16x8*)(pAl + aoff + i * 1024);
            #pragma unroll
            for (int j = 0; j < 4; ++j) {
                acc[i][j] = __builtin_amdgcn_mfma_f32_16x16x32_bf16(av, bh[j], acc[i][j], 0, 0, 0);
                acc[i][j] = __builtin_amdgcn_mfma_f32_16x16x32_bf16(ah, bv[j], acc[i][j], 0, 0, 0);
                acc[i][j] = __builtin_amdgcn_mfma_f32_16x16x32_bf16(ah, bh[j], acc[i][j], 0, 0, 0);
            }
        }
        __builtin_amdgcn_s_setprio(0);
        asm volatile("s_waitcnt lgkmcnt(0)" ::: "memory");
        __builtin_amdgcn_s_barrier();
    }

    // --- fold: np-order d, per-(i,r) top-2 over j, 16-lane merge, LDS merge ---
    float* mb1 = (float*)&lb[0][0][0];   // [4][256]
    float* mb2 = mb1 + 1024;             // [4][256]
    int*   mi  = (int*)(mb1 + 2048);     // [4][256]

    float e2v[4];
    #pragma unroll
    for (int j = 0; j < 4; ++j)
        e2v[j] = e2[c0 + wn * 64 + j * 16 + (l & 15)];

    #pragma unroll
    for (int i = 0; i < 8; ++i) {
        const float4 x2v = *reinterpret_cast<const float4*>(
            x2 + row0 + wm * 128 + i * 16 + (l >> 4) * 4);
        const float x2a[4] = {x2v.x, x2v.y, x2v.z, x2v.w};
        #pragma unroll
        for (int r = 0; r < 4; ++r) {
            float b1 = 3.4e38f, b2 = 3.4e38f; int ix = 0;
            #pragma unroll
            for (int j = 0; j < 4; ++j) {
                const float d = __fadd_rn(__fmaf_rn(-2.f, acc[i][j][r], x2a[r]), e2v[j]);
                const int cj = c0 + wn * 64 + j * 16 + (l & 15);
                if (d < b1)      { b2 = b1; b1 = d; ix = cj; }
                else if (d < b2) { b2 = d; }
            }
            #pragma unroll
            for (int mm = 1; mm <= 8; mm <<= 1) {
                const float ob1 = __shfl_xor(b1, mm);
                const float ob2 = __shfl_xor(b2, mm);
                const int   oix = __shfl_xor(ix, mm);
                top2_merge(b1, ix, b2, ob1, oix, ob2);
            }
            if ((l & 15) == 0) {
                const int rl = wm * 128 + i * 16 + (l >> 4) * 4 + r;
                mb1[wn * 256 + rl] = b1;
                mb2[wn * 256 + rl] = b2;
                mi [wn * 256 + rl] = ix;
            }
        }
    }
    __syncthreads();
    if (tid < 256) {
        float b1 = mb1[tid], b2 = mb2[tid]; int ix = mi[tid];
        #pragma unroll
        for (int q = 1; q < 4; ++q)
            top2_merge(b1, ix, b2, mb1[q * 256 + tid], mi[q * 256 + tid], mb2[q * 256 + tid]);
        const size_t o = (size_t)ct * M_ROWS + row0 + tid;
        pb1[o] = b1; pb2[o] = b2; pidx[o] = ix;
    }
}

// merge the 32 code-split partials per row; emit idx + ambiguity flags
__global__ __launch_bounds__(256) void combine_kernel(
    const float* __restrict__ pb1, const float* __restrict__ pb2,
    const int* __restrict__ pidx,
    int* __restrict__ idx_i, float* __restrict__ idx_f,
    int* __restrict__ flag_count, int* __restrict__ flag_rows)
{
    const int r = blockIdx.x * 256 + threadIdx.x;
    if (r >= M_ROWS) return;
    float b1 = pb1[r], b2 = pb2[r]; int ix = pidx[r];
    #pragma unroll 4
    for (int ct = 1; ct < 32; ++ct)
        top2_merge(b1, ix, b2, pb1[(size_t)ct * M_ROWS + r],
                   pidx[(size_t)ct * M_ROWS + r], pb2[(size_t)ct * M_ROWS + r]);
    idx_i[r] = ix;
    idx_f[r] = (float)ix;
    if (b2 - b1 < TAU) {
        const int p = atomicAdd(flag_count, 1);
        if (p < MAXFLAG) flag_rows[p] = r;
    }
}

// ---------------------------------------------------------------------------
// FALLBACK (round-3 fp32 path) — only if ws_size too small
// ---------------------------------------------------------------------------
#define BM 64
#define BN 128
#define BH 32
#define PADZ 4
#define PADE 4

__device__ __forceinline__ void stage_transposed(const float* __restrict__ src,
                                                 int row0, int h0,
                                                 float* lds, int R, int ldp) {
    const int nf4 = R * (BH / 4);
    for (int f = threadIdx.x; f < nf4; f += 256) {
        const int r  = f / (BH / 4);
        const int c4 = (f % (BH / 4)) * 4;
        const float4 v = *reinterpret_cast<const float4*>(
            src + (size_t)(row0 + r) * H_DIM + h0 + c4);
        lds[(c4 + 0) * ldp + r] = v.x;
        lds[(c4 + 1) * ldp + r] = v.y;
        lds[(c4 + 2) * ldp + r] = v.z;
        lds[(c4 + 3) * ldp + r] = v.w;
    }
}

__global__ __launch_bounds__(256) void dist_argmin_kernel(
    const float* __restrict__ z, const float* __restrict__ emb,
    const float* __restrict__ x2, const float* __restrict__ e2,
    int* __restrict__ idx_i, float* __restrict__ idx_f,
    int* __restrict__ flag_count, int* __restrict__ flag_rows)
{
    __shared__ float zs[BH * (BM + PADZ)];
    __shared__ float es[BH * (BN + PADE)];
    __shared__ float bd[BM][17];
    __shared__ float bd2[BM][17];
    __shared__ int   bi[BM][17];

    const int row0 = blockIdx.x * BM;
    const int tx = threadIdx.x & 15;
    const int ty = threadIdx.x >> 4;

    float x2r[4];
    #pragma unroll
    for (int i = 0; i < 4; ++i) x2r[i] = x2[row0 + ty * 4 + i];

    float best[4], best2[4];
    int   bidx[4];
    #pragma unroll
    for (int i = 0; i < 4; ++i) { best[i] = 3.4e38f; best2[i] = 3.4e38f; bidx[i] = 0; }

    for (int nt = 0; nt < K_CODES / BN; ++nt) {
        float acc[4][8];
        #pragma unroll
        for (int i = 0; i < 4; ++i)
            #pragma unroll
            for (int j = 0; j < 8; ++j) acc[i][j] = 0.f;

        for (int hc = 0; hc < H_DIM / BH; ++hc) {
            __syncthreads();
            stage_transposed(z,   row0,    hc * BH, zs, BM, BM + PADZ);
            stage_transposed(emb, nt * BN, hc * BH, es, BN, BN + PADE);
            __syncthreads();
            #pragma unroll
            for (int h = 0; h < BH; ++h) {
                const float4 zr = *reinterpret_cast<const float4*>(&zs[h * (BM + PADZ) + ty * 4]);
                const float4 e0 = *reinterpret_cast<const float4*>(&es[h * (BN + PADE) + tx * 4]);
                const float4 e1 = *reinterpret_cast<const float4*>(&es[h * (BN + PADE) + 64 + tx * 4]);
                const float zrv[4] = {zr.x, zr.y, zr.z, zr.w};
                const float ev[8]  = {e0.x, e0.y, e0.z, e0.w, e1.x, e1.y, e1.z, e1.w};
                #pragma unroll
                for (int i = 0; i < 4; ++i)
                    #pragma unroll
                    for (int j = 0; j < 8; ++j)
                        acc[i][j] = fmaf(zrv[i], ev[j], acc[i][j]);
            }
        }
        #pragma unroll
        for (int j = 0; j < 8; ++j) {
            const int code = nt * BN + (j < 4 ? tx * 4 + j : 64 + tx * 4 + (j - 4));
            const float e2v = e2[code];
            #pragma unroll
            for (int i = 0; i < 4; ++i) {
                const float d = __fadd_rn(__fmaf_rn(-2.f, acc[i][j], x2r[i]), e2v);
                if (d < best[i])       { best2[i] = best[i]; best[i] = d; bidx[i] = code; }
                else if (d < best2[i]) { best2[i] = d; }
            }
        }
    }

    __syncthreads();
    #pragma unroll
    for (int i = 0; i < 4; ++i) {
        bd [ty * 4 + i][tx] = best[i];
        bd2[ty * 4 + i][tx] = best2[i];
        bi [ty * 4 + i][tx] = bidx[i];
    }
    __syncthreads();
    if (threadIdx.x < BM) {
        const int r = threadIdx.x;
        float g1 = bd[r][0]; int gi = bi[r][0]; float g2 = bd2[r][0];
        #pragma unroll
        for (int t = 1; t < 16; ++t) {
            const float v = bd[r][t]; const int x = bi[r][t];
            if (v < g1)       { g2 = g1; g1 = v; gi = x; }
            else if (v == g1) { g2 = g1; if (x < gi) gi = x; }
            else              { g2 = fminf(g2, v); }
            g2 = fminf(g2, bd2[r][t]);
        }
        idx_i[row0 + r] = gi;
        idx_f[row0 + r] = (float)gi;
        if (g2 - g1 < TAU) {
            const int p = atomicAdd(flag_count, 1);
            if (p < MAXFLAG) flag_rows[p] = row0 + r;
        }
    }
}

// ---------------------------------------------------------------------------
// fixup: ideal-g (fp64 dot -> fp32) rescore, 4-way ILP fp64 chain
// ---------------------------------------------------------------------------
__global__ __launch_bounds__(256) void fixup_kernel(
    const float* __restrict__ z, const float* __restrict__ emb,
    const float* __restrict__ x2, const float* __restrict__ e2,
    const int* __restrict__ flag_count, const int* __restrict__ flag_rows,
    int* __restrict__ idx_i, float* __restrict__ idx_f)
{
    __shared__ float zrow[H_DIM];
    __shared__ float sd[256];
    __shared__ int   si[256];
    int n = *flag_count; if (n > MAXFLAG) n = MAXFLAG;
    for (int j = blockIdx.x; j < n; j += gridDim.x) {
        const int row = flag_rows[j];
        __syncthreads();
        for (int h = threadIdx.x; h < H_DIM; h += 256)
            zrow[h] = z[(size_t)row * H_DIM + h];
        __syncthreads();
        const float x2r = x2[row];
        float bdv = 3.4e38f; int biv = 0x7fffffff;
        for (int k = threadIdx.x; k < K_CODES; k += 256) {
            const float* ek = emb + (size_t)k * H_DIM;
            double d0 = 0.0, d1 = 0.0, d2 = 0.0, d3 = 0.0;
            for (int h = 0; h < H_DIM; h += 4) {
                const float4 ev = *reinterpret_cast<const float4*>(ek + h);
                const float4 zv = *reinterpret_cast<const float4*>(&zrow[h]);
                d0 = fma((double)zv.x, (double)ev.x, d0);
                d1 = fma((double)zv.y, (double)ev.y, d1);
                d2 = fma((double)zv.z, (double)ev.z, d2);
                d3 = fma((double)zv.w, (double)ev.w, d3);
            }
            const float gf = (float)((d0 + d1) + (d2 + d3));
            const float d = __fadd_rn(__fmaf_rn(-2.f, gf, x2r), e2[k]);
            if (d < bdv) { bdv = d; biv = k; }
        }
        sd[threadIdx.x] = bdv; si[threadIdx.x] = biv;
        __syncthreads();
        for (int s = 128; s; s >>= 1) {
            if (threadIdx.x < s) {
                const float od = sd[threadIdx.x + s]; const int oi = si[threadIdx.x + s];
                if (od < sd[threadIdx.x] ||
                    (od == sd[threadIdx.x] && oi < si[threadIdx.x])) {
                    sd[threadIdx.x] = od; si[threadIdx.x] = oi;
                }
            }
            __syncthreads();
        }
        if (threadIdx.x == 0) { idx_i[row] = si[0]; idx_f[row] = (float)si[0]; }
        __syncthreads();
    }
}

// ---------------------------------------------------------------------------
// z_st = z + (z_q - z) + both losses; float4 vectorized
// ---------------------------------------------------------------------------
__global__ __launch_bounds__(256) void epilogue_kernel(
    const float* __restrict__ z, const float* __restrict__ emb,
    const int* __restrict__ idx_i,
    float* __restrict__ z_st, float* __restrict__ loss_slots)
{
    const int NQ = M_ROWS * (H_DIM / 4);
    const float4* z4 = reinterpret_cast<const float4*>(z);
    const float4* e4 = reinterpret_cast<const float4*>(emb);
    float4* o4 = reinterpret_cast<float4*>(z_st);
    float local = 0.f;
    for (int q = blockIdx.x * 256 + threadIdx.x; q < NQ; q += gridDim.x * 256) {
        const int r  = q >> 7;
        const int h4 = q & 127;
        const float4 zq = e4[(size_t)idx_i[r] * 128 + h4];
        const float4 zv = z4[q];
        float4 t, o;
        t.x = zq.x - zv.x; o.x = zv.x + t.x;
        t.y = zq.y - zv.y; o.y = zv.y + t.y;
        t.z = zq.z - zv.z; o.z = zv.z + t.z;
        t.w = zq.w - zv.w; o.w = zv.w + t.w;
        o4[q] = o;
        local = fmaf(t.x, t.x, local);
        local = fmaf(t.y, t.y, local);
        local = fmaf(t.z, t.z, local);
        local = fmaf(t.w, t.w, local);
    }
    #pragma unroll
    for (int off = 32; off; off >>= 1) local += __shfl_down(local, off);
    __shared__ float part[4];
    const int lane = threadIdx.x & 63, wid = threadIdx.x >> 6;
    if (lane == 0) part[wid] = local;
    __syncthreads();
    if (threadIdx.x == 0) {
        const float s = (part[0] + part[1] + part[2] + part[3])
                        * (1.f / (float)((size_t)M_ROWS * H_DIM));
        atomicAdd(&loss_slots[0], s);
        atomicAdd(&loss_slots[1], s);
    }
}

// ---------------------------------------------------------------------------
extern "C" void kernel_launch(void* const* d_in, const int* in_sizes, int n_in,
                              void* d_out, int out_size, void* d_ws, size_t ws_size,
                              hipStream_t stream) {
    const float* z   = (const float*)d_in[0];
    const float* emb = (const float*)d_in[1];

    float* out   = (float*)d_out;
    float* z_st  = out;
    float* idx_f = out + (size_t)M_ROWS * H_DIM;
    float* loss  = out + (size_t)M_ROWS * H_DIM + M_ROWS;

    // partials live temporarily in the z_st output region (dead until epilogue)
    float* pb1  = z_st;                               // 32*32768 f32 = 4 MB
    float* pb2  = z_st + (size_t)32 * M_ROWS;         // 4 MB
    int*   pidx = (int*)(z_st + (size_t)64 * M_ROWS); // 4 MB

    char* ws = (char*)d_ws;
    float* e2     = (float*)(ws + 0);
    float* x2     = (float*)(ws + 32768);
    int*   idx_i  = (int*)  (ws + 163840);
    int*   fcount = (int*)  (ws + 294912);
    int*   frows  = (int*)  (ws + 294976);
    unsigned short* zh = (unsigned short*)(ws + 426048);
    unsigned short* zl = (unsigned short*)(ws + 426048 + 33554432ull);
    unsigned short* eh = (unsigned short*)(ws + 426048 + 67108864ull);
    unsigned short* el = (unsigned short*)(ws + 426048 + 75497472ull);
    const size_t REQ = 426048ull + 83886080ull;   // ~80.4 MB

    hipLaunchKernelGGL(rowsq_all_kernel, dim3((M_ROWS + K_CODES) / 8), dim3(256), 0, stream,
                       z, emb, x2, e2, loss, fcount);

    if (ws_size >= REQ) {
        const int totq = (M_ROWS * H_DIM + K_CODES * H_DIM) / 4;
        hipLaunchKernelGGL(split_all_kernel, dim3(totq / 256), dim3(256), 0, stream,
                           z, emb, zh, zl, eh, el);
        hipLaunchKernelGGL(mfma_dist_kernel, dim3(4096), dim3(512), 0, stream,
                           zh, zl, eh, el, x2, e2, pb1, pb2, pidx);
        hipLaunchKernelGGL(combine_kernel, dim3(M_ROWS / 256), dim3(256), 0, stream,
                           pb1, pb2, pidx, idx_i, idx_f, fcount, frows);
    } else {
        hipLaunchKernelGGL(dist_argmin_kernel, dim3(M_ROWS / BM), dim3(256), 0, stream,
                           z, emb, x2, e2, idx_i, idx_f, fcount, frows);
    }

    hipLaunchKernelGGL(fixup_kernel, dim3(1024), dim3(256), 0, stream,
                       z, emb, x2, e2, fcount, frows, idx_i, idx_f);
    hipLaunchKernelGGL(epilogue_kernel, dim3(2048), dim3(256), 0, stream,
                       z, emb, idx_i, z_st, loss);
}